// Round 11
// baseline (611.175 us; speedup 1.0000x reference)
//
#include <hip/hip_runtime.h>
#include <hip/hip_bf16.h>
#include <stdint.h>

#define B_DIM 16384
#define D_DIM 512
// Embeddings quantized as fp8(8*x): dot scales by 64. logit = dot/64/T.
#define LOGIT_SCALE (1.0f / (0.07f * 64.0f))

typedef int i32x4 __attribute__((ext_vector_type(4)));
typedef int i32x8 __attribute__((ext_vector_type(8)));
typedef float f32x16 __attribute__((ext_vector_type(16)));

// Fragment-linear fp8 layout for 32x32x64 MX fragments (Pn and Tn identical):
//   chunk(RB = row>>5, KT = k>>6) = (RB*8 + KT)*2048 bytes   (32 rows x 64 k)
//   within: half = (k>>4)&1 -> +half*1024
//           lane = ((k>>5)&1)*32 + (row&31) -> +lane*16
//           byte = k&15
// => one 32x32x64 fragment (lane: row=l&31, kb=l>>5; 32 B/lane) = two
//    contiguous 1-KB wave reads (lo at +0, hi at +1024): perfectly coalesced,
//    no LDS anywhere. Layout+intrinsic+epilogue refcheck'd in r6.

// One wave per row: load 512 fp32, L2-normalize, scale by 8, quantize e4m3,
// write one 8-B fragment slot per lane.
__global__ __launch_bounds__(256) void normalize_kernel(const float* __restrict__ in,
                                                        uint8_t* __restrict__ out) {
  int wid = threadIdx.x >> 6;
  int lane = threadIdx.x & 63;
  int row = blockIdx.x * 4 + wid;
  const float* r = in + (size_t)row * D_DIM;
  float4 v0 = ((const float4*)r)[lane * 2];
  float4 v1 = ((const float4*)r)[lane * 2 + 1];
  float ssq = v0.x * v0.x + v0.y * v0.y + v0.z * v0.z + v0.w * v0.w +
              v1.x * v1.x + v1.y * v1.y + v1.z * v1.z + v1.w * v1.w;
#pragma unroll
  for (int m = 1; m < 64; m <<= 1) ssq += __shfl_xor(ssq, m);
  float s8 = 8.0f / fmaxf(sqrtf(ssq), 1e-12f);
  int w0 = __builtin_amdgcn_cvt_pk_fp8_f32(v0.x * s8, v0.y * s8, 0, false);
  w0 = __builtin_amdgcn_cvt_pk_fp8_f32(v0.z * s8, v0.w * s8, w0, true);
  int w1 = __builtin_amdgcn_cvt_pk_fp8_f32(v1.x * s8, v1.y * s8, 0, false);
  w1 = __builtin_amdgcn_cvt_pk_fp8_f32(v1.z * s8, v1.w * s8, w1, true);
  // lane covers k = lane*8 .. lane*8+7:
  //   KT = lane>>3, kb = (lane>>2)&1, half = (lane>>1)&1, low8 = (lane&1)*8
  size_t addr = ((size_t)(row >> 5) * 8 + (lane >> 3)) * 2048 +
                (size_t)((lane >> 1) & 1) * 1024 +
                (size_t)((((lane >> 2) & 1) << 5) | (row & 31)) * 16 +
                (lane & 1) * 8;
  uint2 o;
  o.x = (unsigned)w0;
  o.y = (unsigned)w1;
  *(uint2*)(out + addr) = o;
}

// LDS-free MX-fp8 128x128-tile NT GEMM: 4 waves (2Mx2N), each wave 64x64 out
// as 2x2 32x32 tiles, mfma_scale_f32_32x32x64_f8f6f4 with unity e8m0 scales.
// Fragments loaded straight from L2 (two coalesced 1-KB wave reads each).
// Zero barriers, zero LDS; depth-1 register double-buffer, static indices.
// Fused exp + row/col sums + diag.
__global__ __launch_bounds__(256, 2) void infonce_main(const uint8_t* __restrict__ P,
                                                       const uint8_t* __restrict__ T,
                                                       float* __restrict__ row_sum,
                                                       float* __restrict__ col_sum,
                                                       float* __restrict__ diag) {
  // XCD raster (r2-proven): xcd owns 16 brow strips; within XCD, brow fastest.
  int bid = blockIdx.x;          // 0..16383
  int xcd = bid & 7;
  int q = bid >> 3;              // 0..2047
  int brow = (xcd * 16 + (q & 15)) << 7;
  int bcol = (q >> 4) << 7;

  int tid = threadIdx.x;
  int lane = tid & 63;
  int wid = tid >> 6;
  int wr = (wid >> 1) * 64;      // 2 M-waves
  int wc = (wid & 1) * 64;       // 2 N-waves
  int l31 = lane & 31, l5 = lane >> 5;

  // Wave base: RB = (brow+wr)>>5 ; fragment (mt, KT) at +(mt*8 + KT)*2048.
  const uint8_t* pA = P + ((size_t)((brow + wr) >> 5) * 8) * 2048 + (size_t)lane * 16;
  const uint8_t* pB = T + ((size_t)((bcol + wc) >> 5) * 8) * 2048 + (size_t)lane * 16;

#define LDFRAG(dst, ptr)                                                       \
  do {                                                                         \
    i32x4 lo_ = *(const i32x4*)(ptr);                                          \
    i32x4 hi_ = *(const i32x4*)((ptr) + 1024);                                 \
    dst = __builtin_shufflevector(lo_, hi_, 0, 1, 2, 3, 4, 5, 6, 7);           \
  } while (0)

  f32x16 acc[2][2] = {};

  i32x8 a[2], b[2];
  LDFRAG(a[0], pA + 0 * 2048);
  LDFRAG(a[1], pA + 8 * 2048);
  LDFRAG(b[0], pB + 0 * 2048);
  LDFRAG(b[1], pB + 8 * 2048);

#pragma unroll
  for (int t = 0; t < 8; ++t) {
    i32x8 an[2], bn[2];
    if (t < 7) {
      LDFRAG(an[0], pA + (t + 1) * 2048);
      LDFRAG(an[1], pA + (8 + t + 1) * 2048);
      LDFRAG(bn[0], pB + (t + 1) * 2048);
      LDFRAG(bn[1], pB + (8 + t + 1) * 2048);
    }
#pragma unroll
    for (int mt = 0; mt < 2; ++mt)
#pragma unroll
      for (int nt = 0; nt < 2; ++nt)
        acc[mt][nt] = __builtin_amdgcn_mfma_scale_f32_32x32x64_f8f6f4(
            a[mt], b[nt], acc[mt][nt], 0, 0, 0, 0x7F7F7F7F, 0, 0x7F7F7F7F);
    if (t < 7) {
      a[0] = an[0];
      a[1] = an[1];
      b[0] = bn[0];
      b[1] = bn[1];
    }
  }
#undef LDFRAG

  // Epilogue. 32x32 C/D map (m74/m101, r6-refcheck'd):
  //   row = (j&3) + 8*(j>>2) + 4*l5, col = l31.
#pragma unroll
  for (int mt = 0; mt < 2; ++mt)
#pragma unroll
    for (int nt = 0; nt < 2; ++nt)
#pragma unroll
      for (int j = 0; j < 16; ++j) {
        float logit = acc[mt][nt][j] * LOGIT_SCALE;
        int grow = brow + wr + mt * 32 + (j & 3) + 8 * (j >> 2) + 4 * l5;
        int gcol = bcol + wc + nt * 32 + l31;
        if (grow == gcol) diag[grow] = logit;
        acc[mt][nt][j] = __expf(logit);
      }

  // Row sums: sum the 2 n-tiles, then reduce across the 32-lane col group.
#pragma unroll
  for (int mt = 0; mt < 2; ++mt)
#pragma unroll
    for (int j = 0; j < 16; ++j) {
      float rs = acc[mt][0][j] + acc[mt][1][j];
      rs += __shfl_xor(rs, 1);
      rs += __shfl_xor(rs, 2);
      rs += __shfl_xor(rs, 4);
      rs += __shfl_xor(rs, 8);
      rs += __shfl_xor(rs, 16);
      if (l31 == 0)
        atomicAdd(&row_sum[brow + wr + mt * 32 + (j & 3) + 8 * (j >> 2) + 4 * l5], rs);
    }

  // Col sums: sum regs (16 rows) over mt, then the two lane-half row groups.
#pragma unroll
  for (int nt = 0; nt < 2; ++nt) {
    float cs = 0.f;
#pragma unroll
    for (int mt = 0; mt < 2; ++mt)
#pragma unroll
      for (int j = 0; j < 16; ++j) cs += acc[mt][nt][j];
    cs += __shfl_xor(cs, 32);
    if (l5 == 0) atomicAdd(&col_sum[bcol + wc + nt * 32 + l31], cs);
  }
}

__global__ __launch_bounds__(256) void finalize_kernel(const float* __restrict__ rs,
                                                       const float* __restrict__ cs,
                                                       const float* __restrict__ dg,
                                                       float* __restrict__ out) {
  float s = 0.f;
  for (int i = threadIdx.x; i < B_DIM; i += 256)
    s += 0.5f * (logf(rs[i]) + logf(cs[i])) - dg[i];
#pragma unroll
  for (int m = 1; m < 64; m <<= 1) s += __shfl_xor(s, m);
  __shared__ float red[4];
  if ((threadIdx.x & 63) == 0) red[threadIdx.x >> 6] = s;
  __syncthreads();
  if (threadIdx.x == 0)
    out[0] = (red[0] + red[1] + red[2] + red[3]) * (1.0f / (float)B_DIM);
}

extern "C" void kernel_launch(void* const* d_in, const int* in_sizes, int n_in,
                              void* d_out, int out_size, void* d_ws, size_t ws_size,
                              hipStream_t stream) {
  const float* p = (const float*)d_in[0];
  const float* t = (const float*)d_in[1];
  float* out = (float*)d_out;

  char* ws = (char*)d_ws;
  const size_t embBytes = (size_t)B_DIM * D_DIM;  // 8 MB fp8
  uint8_t* Pn = (uint8_t*)ws;
  uint8_t* Tn = (uint8_t*)(ws + embBytes);
  float* row_sum = (float*)(ws + 2 * embBytes);
  float* col_sum = row_sum + B_DIM;
  float* diag = col_sum + B_DIM;

  hipMemsetAsync(row_sum, 0, 2 * (size_t)B_DIM * sizeof(float), stream);
  normalize_kernel<<<B_DIM / 4, 256, 0, stream>>>(p, Pn);
  normalize_kernel<<<B_DIM / 4, 256, 0, stream>>>(t, Tn);
  infonce_main<<<(B_DIM / 128) * (B_DIM / 128), 256, 0, stream>>>(Pn, Tn, row_sum, col_sum, diag);
  finalize_kernel<<<1, 256, 0, stream>>>(row_sum, col_sum, diag, out);
}

// Round 12
// 278.649 us; speedup vs baseline: 2.1933x; 2.1933x over previous
//
#include <hip/hip_runtime.h>
#include <hip/hip_bf16.h>
#include <stdint.h>

#define B_DIM 16384
#define D_DIM 512
// Embeddings quantized as int8 q = rne(127*x): dot scales by 127^2.
// logit = dot_int / (127^2 * 0.07)
#define ILOGIT_SCALE (1.0f / (127.0f * 127.0f * 0.07f))

typedef int i32x4 __attribute__((ext_vector_type(4)));
typedef float f32x4 __attribute__((ext_vector_type(4)));

// Fragment-linear i8 layout (identical for Pn and Tn), BK=64 chunks:
//   chunk(RB = row>>7, KT = k>>6) = (RB*8 + KT)*8192 bytes  (128 rows x 64 k)
//   subtile mq = (row>>4)&7 -> 1 KB at mq*1024
//   slot lane = ((k>>4)&3)*16 + (row&15) -> 16 B at lane*16
//   byte = k&15   (CONTIGUOUS k per lane: i8 16x16x64 lane holds k=rlane*16..+15,
//                  per the m89-verified gfx950 2xK-contiguous convention)
// => one i8 16x16x64 MFMA fragment = ONE contiguous 1-KB wave read
//    (coalesced global_load_dwordx4, no LDS anywhere).

// One wave per row: load 512 fp32, L2-normalize, quantize q=rne(127x) (|x|<=1
// so never clips), write one 8-B fragment slot per lane.
__global__ __launch_bounds__(256) void normalize_kernel(const float* __restrict__ in,
                                                        uint8_t* __restrict__ out) {
  int wid = threadIdx.x >> 6;
  int lane = threadIdx.x & 63;
  int row = blockIdx.x * 4 + wid;
  const float* r = in + (size_t)row * D_DIM;
  float4 v0 = ((const float4*)r)[lane * 2];
  float4 v1 = ((const float4*)r)[lane * 2 + 1];
  float ssq = v0.x * v0.x + v0.y * v0.y + v0.z * v0.z + v0.w * v0.w +
              v1.x * v1.x + v1.y * v1.y + v1.z * v1.z + v1.w * v1.w;
#pragma unroll
  for (int m = 1; m < 64; m <<= 1) ssq += __shfl_xor(ssq, m);
  float s = 127.0f / fmaxf(sqrtf(ssq), 1e-12f);
  int q0 = __float2int_rn(v0.x * s), q1 = __float2int_rn(v0.y * s);
  int q2 = __float2int_rn(v0.z * s), q3 = __float2int_rn(v0.w * s);
  int q4 = __float2int_rn(v1.x * s), q5 = __float2int_rn(v1.y * s);
  int q6 = __float2int_rn(v1.z * s), q7 = __float2int_rn(v1.w * s);
  uint2 o;
  o.x = (uint32_t)(q0 & 255) | ((uint32_t)(q1 & 255) << 8) |
        ((uint32_t)(q2 & 255) << 16) | ((uint32_t)q3 << 24);
  o.y = (uint32_t)(q4 & 255) | ((uint32_t)(q5 & 255) << 8) |
        ((uint32_t)(q6 & 255) << 16) | ((uint32_t)q7 << 24);
  // lane covers k = lane*8 .. lane*8+7:
  //   KT = lane>>3, slot rlane = (k>>4)&3 = (lane>>1)&3, byte = (lane&1)*8
  size_t addr = ((size_t)(row >> 7) * 8 + (lane >> 3)) * 8192 +
                (size_t)((row >> 4) & 7) * 1024 +
                (size_t)((((lane >> 1) & 3) << 4) | (row & 15)) * 16 +
                (lane & 1) * 8;
  *(uint2*)(out + addr) = o;
}

// LDS-free i8 128x128-tile NT GEMM (r10 structure, i8 engine): 4 waves
// (2Mx2N), each wave 64x64 out, mfma_i32_16x16x64_i8 (2x fp8 rate), exact
// int32 accumulation. Fragments straight from L2 (coalesced 1-KB wave
// reads). Zero barriers, zero LDS; depth-1 register double-buffer, static
// indices. Fused exp + row/col sums + diag.
__global__ __launch_bounds__(256, 3) void infonce_main(const uint8_t* __restrict__ P,
                                                       const uint8_t* __restrict__ T,
                                                       float* __restrict__ row_sum,
                                                       float* __restrict__ col_sum,
                                                       float* __restrict__ diag) {
  // XCD raster (r2-proven): xcd owns 16 brow strips (2048 rows = 1 MB A,
  // L2-resident); within XCD, brow fastest -> concurrent blocks share bcol.
  int bid = blockIdx.x;          // 0..16383
  int xcd = bid & 7;
  int q = bid >> 3;              // 0..2047
  int brow = (xcd * 16 + (q & 15)) << 7;
  int bcol = (q >> 4) << 7;

  int tid = threadIdx.x;
  int lane = tid & 63;
  int wid = tid >> 6;
  int wr = (wid >> 1) * 64;      // 2 M-waves
  int wc = (wid & 1) * 64;       // 2 N-waves
  int rlane = lane >> 4;
  int clane = lane & 15;

  // Wave's fragment base (fragment m/n at K-tile kt: + kt*8192 + m*1024).
  const uint8_t* pA = P + ((size_t)(brow >> 7) * 8) * 8192 +
                      (size_t)((wid >> 1) * 4) * 1024 + (size_t)lane * 16;
  const uint8_t* pB = T + ((size_t)(bcol >> 7) * 8) * 8192 +
                      (size_t)((wid & 1) * 4) * 1024 + (size_t)lane * 16;

  i32x4 acc[4][4] = {};

  i32x4 a[4], b[4];
#pragma unroll
  for (int m = 0; m < 4; ++m) a[m] = *(const i32x4*)(pA + m * 1024);
#pragma unroll
  for (int n = 0; n < 4; ++n) b[n] = *(const i32x4*)(pB + n * 1024);

#pragma unroll
  for (int t = 0; t < 8; ++t) {
    i32x4 an[4], bn[4];
    if (t < 7) {
#pragma unroll
      for (int m = 0; m < 4; ++m)
        an[m] = *(const i32x4*)(pA + (t + 1) * 8192 + m * 1024);
#pragma unroll
      for (int n = 0; n < 4; ++n)
        bn[n] = *(const i32x4*)(pB + (t + 1) * 8192 + n * 1024);
    }
#pragma unroll
    for (int m = 0; m < 4; ++m)
#pragma unroll
      for (int n = 0; n < 4; ++n)
        acc[m][n] = __builtin_amdgcn_mfma_i32_16x16x64_i8(a[m], b[n], acc[m][n], 0, 0, 0);
    if (t < 7) {
#pragma unroll
      for (int m = 0; m < 4; ++m) a[m] = an[m];
#pragma unroll
      for (int n = 0; n < 4; ++n) b[n] = bn[n];
    }
  }

  // Epilogue: logit = acc_int * ILOGIT_SCALE; capture diagonal; exp in place.
  f32x4 ex[4][4];
#pragma unroll
  for (int m = 0; m < 4; ++m)
#pragma unroll
    for (int n = 0; n < 4; ++n)
#pragma unroll
      for (int j = 0; j < 4; ++j) {
        float logit = (float)acc[m][n][j] * ILOGIT_SCALE;
        int grow = brow + wr + m * 16 + rlane * 4 + j;
        int gcol = bcol + wc + n * 16 + clane;
        if (grow == gcol) diag[grow] = logit;
        ex[m][n][j] = __expf(logit);
      }

  // Row sums: reduce over n-fragments then across the 16-lane column group.
#pragma unroll
  for (int m = 0; m < 4; ++m)
#pragma unroll
    for (int j = 0; j < 4; ++j) {
      float rs = ex[m][0][j] + ex[m][1][j] + ex[m][2][j] + ex[m][3][j];
      rs += __shfl_xor(rs, 1);
      rs += __shfl_xor(rs, 2);
      rs += __shfl_xor(rs, 4);
      rs += __shfl_xor(rs, 8);
      if (clane == 0) atomicAdd(&row_sum[brow + wr + m * 16 + rlane * 4 + j], rs);
    }

  // Col sums: reduce over m-fragments and regs, then across the 4 row groups.
#pragma unroll
  for (int n = 0; n < 4; ++n) {
    float cs = 0.f;
#pragma unroll
    for (int m = 0; m < 4; ++m)
#pragma unroll
      for (int j = 0; j < 4; ++j) cs += ex[m][n][j];
    cs += __shfl_xor(cs, 16);
    cs += __shfl_xor(cs, 32);
    if (rlane == 0) atomicAdd(&col_sum[bcol + wc + n * 16 + clane], cs);
  }
}

__global__ __launch_bounds__(256) void finalize_kernel(const float* __restrict__ rs,
                                                       const float* __restrict__ cs,
                                                       const float* __restrict__ dg,
                                                       float* __restrict__ out) {
  float s = 0.f;
  for (int i = threadIdx.x; i < B_DIM; i += 256)
    s += 0.5f * (logf(rs[i]) + logf(cs[i])) - dg[i];
#pragma unroll
  for (int m = 1; m < 64; m <<= 1) s += __shfl_xor(s, m);
  __shared__ float red[4];
  if ((threadIdx.x & 63) == 0) red[threadIdx.x >> 6] = s;
  __syncthreads();
  if (threadIdx.x == 0)
    out[0] = (red[0] + red[1] + red[2] + red[3]) * (1.0f / (float)B_DIM);
}

extern "C" void kernel_launch(void* const* d_in, const int* in_sizes, int n_in,
                              void* d_out, int out_size, void* d_ws, size_t ws_size,
                              hipStream_t stream) {
  const float* p = (const float*)d_in[0];
  const float* t = (const float*)d_in[1];
  float* out = (float*)d_out;

  char* ws = (char*)d_ws;
  const size_t embBytes = (size_t)B_DIM * D_DIM;  // 8 MB i8
  uint8_t* Pn = (uint8_t*)ws;
  uint8_t* Tn = (uint8_t*)(ws + embBytes);
  float* row_sum = (float*)(ws + 2 * embBytes);
  float* col_sum = row_sum + B_DIM;
  float* diag = col_sum + B_DIM;

  hipMemsetAsync(row_sum, 0, 2 * (size_t)B_DIM * sizeof(float), stream);
  normalize_kernel<<<B_DIM / 4, 256, 0, stream>>>(p, Pn);
  normalize_kernel<<<B_DIM / 4, 256, 0, stream>>>(t, Tn);
  infonce_main<<<(B_DIM / 128) * (B_DIM / 128), 256, 0, stream>>>(Pn, Tn, row_sum, col_sum, diag);
  finalize_kernel<<<1, 256, 0, stream>>>(row_sum, col_sum, diag, out);
}